// Round 2
// baseline (241.508 us; speedup 1.0000x reference)
//
#include <hip/hip_runtime.h>
#include <cstdint>
#include <cstddef>

typedef __bf16 bf16_t;
typedef bf16_t bf16x8 __attribute__((ext_vector_type(8)));
typedef float f32x4 __attribute__((ext_vector_type(4)));

__device__ inline bf16x8 load8(const float* p) {
  f32x4 a = *reinterpret_cast<const f32x4*>(p);
  f32x4 b = *reinterpret_cast<const f32x4*>(p + 4);
  bf16x8 r;
  r[0] = (bf16_t)a[0]; r[1] = (bf16_t)a[1];
  r[2] = (bf16_t)a[2]; r[3] = (bf16_t)a[3];
  r[4] = (bf16_t)b[0]; r[5] = (bf16_t)b[1];
  r[6] = (bf16_t)b[2]; r[7] = (bf16_t)b[3];
  return r;
}
__device__ inline bf16x8 load8(const bf16_t* p) {
  return *reinterpret_cast<const bf16x8*>(p);
}

// ---------------------------------------------------------------------------
// x fp32 -> bf16 (flat copy).
// ---------------------------------------------------------------------------
__global__ __launch_bounds__(256) void cvtx_k(const float* __restrict__ x,
                                              bf16_t* __restrict__ xb) {
  const size_t i = (size_t)blockIdx.x * 2048 + (size_t)threadIdx.x * 8;
  *reinterpret_cast<bf16x8*>(xb + i) = load8(x + i);
}

// ---------------------------------------------------------------------------
// Weights fp32 [K][N] -> bf16 transposed [N][K] (K=1024), 64x64 LDS tiles.
// Segments: Wq 256 tiles | Wk 64 | Wv 64 | Wo 256  -> 640 blocks.
// ---------------------------------------------------------------------------
__global__ __launch_bounds__(256) void cvtT_k(
    const float* __restrict__ Wq, const float* __restrict__ Wk,
    const float* __restrict__ Wv, const float* __restrict__ Wo,
    bf16_t* __restrict__ wqT, bf16_t* __restrict__ wkT,
    bf16_t* __restrict__ wvT, bf16_t* __restrict__ woT) {
  __shared__ bf16_t Ts[64][72];
  const int b = blockIdx.x;
  const float* S;
  bf16_t* D;
  int N, idx;
  if (b < 256) { S = Wq; D = wqT; N = 1024; idx = b; }
  else if (b < 320) { S = Wk; D = wkT; N = 256; idx = b - 256; }
  else if (b < 384) { S = Wv; D = wvT; N = 256; idx = b - 320; }
  else { S = Wo; D = woT; N = 1024; idx = b - 384; }
  const int ntl = (N == 1024) ? 4 : 2;  // log2(n-tiles)
  const int kt0 = (idx >> ntl) * 64;
  const int n0 = (idx & ((1 << ntl) - 1)) * 64;
  const int tid = threadIdx.x;
#pragma unroll
  for (int i = 0; i < 2; ++i) {
    const int c = tid + 256 * i;
    const int row = c >> 3, col0 = (c & 7) * 8;
    *reinterpret_cast<bf16x8*>(&Ts[row][col0]) =
        load8(&S[(size_t)(kt0 + row) * N + n0 + col0]);
  }
  __syncthreads();
#pragma unroll
  for (int i = 0; i < 2; ++i) {
    const int c = tid + 256 * i;
    const int nrow = c >> 3, k0 = (c & 7) * 8;
    bf16x8 v;
#pragma unroll
    for (int j = 0; j < 8; ++j) v[j] = Ts[k0 + j][nrow];
    *reinterpret_cast<bf16x8*>(&D[(size_t)(n0 + nrow) * 1024 + kt0 + k0]) = v;
  }
}

// ---------------------------------------------------------------------------
// 128x128 GEMM body, B^T form: C = A[M,K] * BT[N,K]^T, all bf16, BK=32,
// software-pipelined staging, both operands staged as contiguous b128 rows.
// MFMA layouts (verified m89):
//   A: lane holds A[m=lane&15][k=(lane>>4)*8+j]
//   B: lane holds B[k=(lane>>4)*8+j][n=lane&15]  (= BT[n][k] rows)
//   C/D: row=(lane>>4)*4+reg, col=lane&15
// ---------------------------------------------------------------------------
template <typename OutT>
__device__ inline void gemm_bt_body(const bf16_t* __restrict__ A,
                                    const bf16_t* __restrict__ BT,
                                    OutT* __restrict__ C, int m0, int bt0,
                                    int K, int CN, int cn0, float alpha) {
  __shared__ __align__(16) bf16_t As[128][40];
  __shared__ __align__(16) bf16_t Bs[128][40];  // [n][k]

  const int tid = threadIdx.x;
  const int wave = tid >> 6, lane = tid & 63;
  const int quad = lane >> 4, l16 = lane & 15;
  const int moff = (wave & 1) * 64, noff = (wave >> 1) * 64;

  f32x4 acc[4][4];
#pragma unroll
  for (int mt = 0; mt < 4; ++mt)
#pragma unroll
    for (int nt = 0; nt < 4; ++nt) acc[mt][nt] = {0.f, 0.f, 0.f, 0.f};

  const int arow = tid >> 1, ak0 = (tid & 1) * 16;

  bf16x8 a0, a1, b0, b1;
  {
    const bf16_t* ap = &A[(size_t)(m0 + arow) * K + ak0];
    a0 = load8(ap); a1 = load8(ap + 8);
    const bf16_t* bp = &BT[(size_t)(bt0 + arow) * K + ak0];
    b0 = load8(bp); b1 = load8(bp + 8);
  }

  for (int k0 = 0; k0 < K; k0 += 32) {
    *reinterpret_cast<bf16x8*>(&As[arow][ak0]) = a0;
    *reinterpret_cast<bf16x8*>(&As[arow][ak0 + 8]) = a1;
    *reinterpret_cast<bf16x8*>(&Bs[arow][ak0]) = b0;
    *reinterpret_cast<bf16x8*>(&Bs[arow][ak0 + 8]) = b1;
    __syncthreads();
    if (k0 + 32 < K) {
      const bf16_t* ap = &A[(size_t)(m0 + arow) * K + k0 + 32 + ak0];
      a0 = load8(ap); a1 = load8(ap + 8);
      const bf16_t* bp = &BT[(size_t)(bt0 + arow) * K + k0 + 32 + ak0];
      b0 = load8(bp); b1 = load8(bp + 8);
    }
    bf16x8 af[4], bfr[4];
#pragma unroll
    for (int mt = 0; mt < 4; ++mt)
      af[mt] =
          *reinterpret_cast<const bf16x8*>(&As[moff + mt * 16 + l16][quad * 8]);
#pragma unroll
    for (int nt = 0; nt < 4; ++nt)
      bfr[nt] =
          *reinterpret_cast<const bf16x8*>(&Bs[noff + nt * 16 + l16][quad * 8]);
#pragma unroll
    for (int mt = 0; mt < 4; ++mt)
#pragma unroll
      for (int nt = 0; nt < 4; ++nt)
        acc[mt][nt] = __builtin_amdgcn_mfma_f32_16x16x32_bf16(
            af[mt], bfr[nt], acc[mt][nt], 0, 0, 0);
    __syncthreads();
  }

#pragma unroll
  for (int mt = 0; mt < 4; ++mt) {
    const int crow = m0 + moff + mt * 16 + quad * 4;
#pragma unroll
    for (int nt = 0; nt < 4; ++nt) {
      const int ccol = cn0 + noff + nt * 16 + l16;
#pragma unroll
      for (int r = 0; r < 4; ++r)
        C[(size_t)(crow + r) * CN + ccol] = (OutT)(acc[mt][nt][r] * alpha);
    }
  }
}

// Fused QKV projection: n-tiles [Wq 0..7 | Wk 8..9 | Wv 10..11], B^T weights.
__global__ __launch_bounds__(256, 3) void qkv_k(
    const bf16_t* __restrict__ x, const bf16_t* __restrict__ wqT,
    const bf16_t* __restrict__ wkT, const bf16_t* __restrict__ wvT,
    bf16_t* __restrict__ Qo, bf16_t* __restrict__ Ko, bf16_t* __restrict__ Vo) {
  const int n0 = blockIdx.x * 128;
  const int m0 = blockIdx.y * 128;
  const bf16_t* BT;
  bf16_t* C;
  int CN, bn0;
  float alpha;
  if (n0 < 1024) {
    BT = wqT; C = Qo; CN = 1024; bn0 = n0; alpha = 0.125f;  // attn scale
  } else if (n0 < 1280) {
    BT = wkT; C = Ko; CN = 256; bn0 = n0 - 1024; alpha = 1.0f;
  } else {
    BT = wvT; C = Vo; CN = 256; bn0 = n0 - 1280; alpha = 1.0f;
  }
  gemm_bt_body<bf16_t>(x, BT, C, m0, bn0, 1024, CN, bn0, alpha);
}

// Plain B^T GEMM (attn @ Wo^T^T).
template <typename OutT>
__global__ __launch_bounds__(256, 3) void gemm_bt_k(
    const bf16_t* __restrict__ A, const bf16_t* __restrict__ BT,
    OutT* __restrict__ C, int K, int N, float alpha) {
  gemm_bt_body<OutT>(A, BT, C, blockIdx.y * 128, blockIdx.x * 128, K, N,
                     blockIdx.x * 128, alpha);
}

// ---------------------------------------------------------------------------
// Transpose V [4096,256] -> VT[(g*4+kh)*64 + d][key].
// ---------------------------------------------------------------------------
__global__ __launch_bounds__(256) void transpose_v_k(
    const bf16_t* __restrict__ V, bf16_t* __restrict__ VT) {
  __shared__ bf16_t Vs[64][72];
  const int tid = threadIdx.x;
  const int kt0 = blockIdx.x * 64;
  const int ghk = blockIdx.y;  // g*4+kh
  const int g = ghk >> 2, kh = ghk & 3;
#pragma unroll
  for (int i = 0; i < 2; ++i) {
    const int c = tid + 256 * i;
    const int row = c >> 3, d0 = (c & 7) * 8;
    *reinterpret_cast<bf16x8*>(&Vs[row][d0]) = *reinterpret_cast<const bf16x8*>(
        &V[((size_t)(kt0 + row) * 2 + g) * 256 + kh * 64 + d0]);
  }
  __syncthreads();
#pragma unroll
  for (int i = 0; i < 2; ++i) {
    const int c = tid + 256 * i;
    const int d = c >> 3, k0 = (c & 7) * 8;
    bf16x8 v;
#pragma unroll
    for (int j = 0; j < 8; ++j) v[j] = Vs[k0 + j][d];
    *reinterpret_cast<bf16x8*>(&VT[((size_t)ghk * 64 + d) * 2048 + kt0 + k0]) =
        v;
  }
}

// ---------------------------------------------------------------------------
// Flash attention v8 = flash6 block geometry (64 q-rows/block, 32 T-tiles,
// 528 key-tile iterations per gh) but 4 waves x 16 q-rows instead of
// 2 waves x 32: doubles wave count to 4096 (occupancy) while keeping the
// iteration count — per-thread staging and per-lane softmax both halve.
// LDS 24 KB (Ks 8K + Vs 8K + Ps[4] 8K) -> 6 blocks/CU, 24 waves/CU cap.
// XCD-balanced causal-T map as flash6 (sum T+1 = 66 per XCD residue).
// ---------------------------------------------------------------------------
__global__ __launch_bounds__(256, 6) void flash8_k(
    const bf16_t* __restrict__ Q, const bf16_t* __restrict__ K,
    const bf16_t* __restrict__ VT, bf16_t* __restrict__ ATTN) {
  __shared__ __align__(16) bf16_t Ks[64][64];
  __shared__ __align__(16) bf16_t Vs[64][64];  // [d][key_local], swizzled
  __shared__ __align__(16) bf16_t Ps[4][16][64];

  const int tid = threadIdx.x;
  const int w = tid >> 6, lane = tid & 63;
  const int quad = lane >> 4, l16 = lane & 15;
  const int b = blockIdx.x;  // 0..31
  const int j8 = b & 7, i8 = b >> 3;
  const int T = (i8 == 0) ? j8
              : (i8 == 1) ? (15 - j8)
              : (i8 == 2) ? (16 + j8)
                          : (31 - j8);
  const int gh = blockIdx.y;
  const int g = gh >> 4, h = gh & 15, kh = h >> 2;
  const int qrow0 = T * 64 + w * 16;  // wave's first query row
  const int swz = ((l16 >> 2) & 3) << 4;
  const int rsw = l16 & 7;  // row-dependent K/V col-block swizzle key

  bf16x8 qf[2];
#pragma unroll
  for (int t = 0; t < 2; ++t)
    qf[t] = *reinterpret_cast<const bf16x8*>(
        &Q[((size_t)(qrow0 + l16) * 2 + g) * 1024 + h * 64 + t * 32 +
           quad * 8]);

  f32x4 O[4];
  f32x4 lp = {0.f, 0.f, 0.f, 0.f};
#pragma unroll
  for (int d = 0; d < 4; ++d) O[d] = {0.f, 0.f, 0.f, 0.f};

  bf16x8 kr[2], vr[2];
#pragma unroll
  for (int i = 0; i < 2; ++i) {
    const int c = tid + 256 * i;
    const int row = c >> 3, e0 = (c & 7) * 8;
    kr[i] = *reinterpret_cast<const bf16x8*>(
        &K[((size_t)(row)*2 + g) * 256 + kh * 64 + e0]);
    vr[i] = *reinterpret_cast<const bf16x8*>(
        &VT[((size_t)(g * 4 + kh) * 64 + row) * 2048 + e0]);
  }

  for (int kt = 0; kt <= T; ++kt) {
#pragma unroll
    for (int i = 0; i < 2; ++i) {
      const int c = tid + 256 * i;
      const int row = c >> 3;
      const int pb = (((c & 7) ^ (row & 7)) << 3);  // swizzled col block
      *reinterpret_cast<bf16x8*>(&Ks[row][pb]) = kr[i];
      *reinterpret_cast<bf16x8*>(&Vs[row][pb]) = vr[i];
    }
    __syncthreads();
    if (kt < T) {
      const int nt0 = (kt + 1) * 64;
#pragma unroll
      for (int i = 0; i < 2; ++i) {
        const int c = tid + 256 * i;
        const int row = c >> 3, e0 = (c & 7) * 8;
        kr[i] = *reinterpret_cast<const bf16x8*>(
            &K[((size_t)(nt0 + row) * 2 + g) * 256 + kh * 64 + e0]);
        vr[i] = *reinterpret_cast<const bf16x8*>(
            &VT[((size_t)(g * 4 + kh) * 64 + row) * 2048 + nt0 + e0]);
      }
    }

    f32x4 s[4];
    __builtin_amdgcn_s_setprio(1);
#pragma unroll
    for (int nt = 0; nt < 4; ++nt) {
      bf16x8 kf0 = *reinterpret_cast<const bf16x8*>(
          &Ks[nt * 16 + l16][(quad ^ rsw) << 3]);
      bf16x8 kf1 = *reinterpret_cast<const bf16x8*>(
          &Ks[nt * 16 + l16][((4 + quad) ^ rsw) << 3]);
      f32x4 z = {0.f, 0.f, 0.f, 0.f};
      z = __builtin_amdgcn_mfma_f32_16x16x32_bf16(qf[0], kf0, z, 0, 0, 0);
      s[nt] = __builtin_amdgcn_mfma_f32_16x16x32_bf16(qf[1], kf1, z, 0, 0, 0);
    }
    __builtin_amdgcn_s_setprio(0);
    const bool diag = (kt == T);
    const int qloc = w * 16 + quad * 4;  // wave-local q row vs tile keys
#pragma unroll
    for (int nt = 0; nt < 4; ++nt) {
      const int key = nt * 16 + l16;
#pragma unroll
      for (int r = 0; r < 4; ++r) {
        float p = __expf(s[nt][r]);
        if (diag && key > qloc + r) p = 0.f;
        lp[r] += p;
        Ps[w][quad * 4 + r][((nt ^ quad) << 4) + l16] = (bf16_t)p;
      }
    }
    bf16x8 pf[2];
#pragma unroll
    for (int t = 0; t < 2; ++t)
      pf[t] = *reinterpret_cast<const bf16x8*>(
          &Ps[w][l16][(t * 32 + quad * 8) ^ swz]);
    __builtin_amdgcn_s_setprio(1);
#pragma unroll
    for (int dnt = 0; dnt < 4; ++dnt) {
      bf16x8 vf0 = *reinterpret_cast<const bf16x8*>(
          &Vs[dnt * 16 + l16][(quad ^ rsw) << 3]);
      bf16x8 vf1 = *reinterpret_cast<const bf16x8*>(
          &Vs[dnt * 16 + l16][((4 + quad) ^ rsw) << 3]);
      O[dnt] = __builtin_amdgcn_mfma_f32_16x16x32_bf16(pf[0], vf0, O[dnt], 0,
                                                       0, 0);
      O[dnt] = __builtin_amdgcn_mfma_f32_16x16x32_bf16(pf[1], vf1, O[dnt], 0,
                                                       0, 0);
    }
    __builtin_amdgcn_s_setprio(0);
    __syncthreads();
  }

#pragma unroll
  for (int off = 1; off < 16; off <<= 1)
#pragma unroll
    for (int r = 0; r < 4; ++r) lp[r] += __shfl_xor(lp[r], off, 64);
#pragma unroll
  for (int r = 0; r < 4; ++r) {
    const float inv = 1.f / lp[r];
    const int row = qrow0 + quad * 4 + r;
#pragma unroll
    for (int dnt = 0; dnt < 4; ++dnt)
      ATTN[((size_t)row * 2 + g) * 1024 + h * 64 + dnt * 16 + l16] =
          (bf16_t)(O[dnt][r] * inv);
  }
}

// ---------------------------------------------------------------------------
extern "C" void kernel_launch(void* const* d_in, const int* in_sizes, int n_in,
                              void* d_out, int out_size, void* d_ws,
                              size_t ws_size, hipStream_t stream) {
  (void)in_sizes;
  (void)n_in;
  (void)out_size;
  (void)ws_size;

  const float* x = (const float*)d_in[0];   // [4096,1024] fp32
  const float* Wq = (const float*)d_in[1];  // [1024,1024]
  const float* Wk = (const float*)d_in[2];  // [1024,256]
  const float* Wv = (const float*)d_in[3];  // [1024,256]
  const float* Wo = (const float*)d_in[4];  // [1024,1024]
  float* out = (float*)d_out;               // [4096,1024] fp32 (16 MB)

  const size_t MB = 1024 * 1024;
  // d_out: [0,8M) Qtmp | [8M,10M) VT | [10M,13M) wqT/wkT/wvT | [13M,15M) Vo
  // (all dead before the final GEMM writes out; final GEMM reads only ws).
  char* ob = (char*)d_out;
  bf16_t* Qtmp = (bf16_t*)ob;
  bf16_t* VTws = (bf16_t*)(ob + 8 * MB);
  bf16_t* wqT = (bf16_t*)(ob + 10 * MB);
  bf16_t* wkT = (bf16_t*)(ob + 12 * MB);
  bf16_t* wvT = (bf16_t*)(ob + 12 * MB + 512 * 1024);
  bf16_t* Vws = (bf16_t*)(ob + 13 * MB);
  // ws (12 MB): [0,2M) K | [2M,4M) woT | [4M,12M) ATTN (xb borrows upfront).
  char* wb = (char*)d_ws;
  bf16_t* Kws = (bf16_t*)wb;
  bf16_t* woT = (bf16_t*)(wb + 2 * MB);
  bf16_t* ATTNws = (bf16_t*)(wb + 4 * MB);
  bf16_t* xb = ATTNws;  // 8 MB, dead once flash starts writing ATTN

  cvtx_k<<<dim3(2048), dim3(256), 0, stream>>>(x, xb);
  cvtT_k<<<dim3(640), dim3(256), 0, stream>>>(Wq, Wk, Wv, Wo, wqT, wkT, wvT,
                                              woT);
  qkv_k<<<dim3(12, 32), dim3(256), 0, stream>>>(xb, wqT, wkT, wvT, Qtmp, Kws,
                                                Vws);
  transpose_v_k<<<dim3(32, 8), dim3(256), 0, stream>>>(Vws, VTws);
  flash8_k<<<dim3(32, 32), dim3(256), 0, stream>>>(Qtmp, Kws, VTws, ATTNws);
  gemm_bt_k<float><<<dim3(8, 32), dim3(256), 0, stream>>>(ATTNws, woT, out,
                                                          1024, 1024, 1.0f);
}

// Round 3
// 187.594 us; speedup vs baseline: 1.2874x; 1.2874x over previous
//
#include <hip/hip_runtime.h>
#include <cstdint>
#include <cstddef>

typedef __bf16 bf16_t;
typedef bf16_t bf16x8 __attribute__((ext_vector_type(8)));
typedef float f32x4 __attribute__((ext_vector_type(4)));

__device__ inline bf16x8 load8(const float* p) {
  f32x4 a = *reinterpret_cast<const f32x4*>(p);
  f32x4 b = *reinterpret_cast<const f32x4*>(p + 4);
  bf16x8 r;
  r[0] = (bf16_t)a[0]; r[1] = (bf16_t)a[1];
  r[2] = (bf16_t)a[2]; r[3] = (bf16_t)a[3];
  r[4] = (bf16_t)b[0]; r[5] = (bf16_t)b[1];
  r[6] = (bf16_t)b[2]; r[7] = (bf16_t)b[3];
  return r;
}
__device__ inline bf16x8 load8(const bf16_t* p) {
  return *reinterpret_cast<const bf16x8*>(p);
}

// ---------------------------------------------------------------------------
// x fp32 -> bf16 (flat copy).
// ---------------------------------------------------------------------------
__global__ __launch_bounds__(256) void cvtx_k(const float* __restrict__ x,
                                              bf16_t* __restrict__ xb) {
  const size_t i = (size_t)blockIdx.x * 2048 + (size_t)threadIdx.x * 8;
  *reinterpret_cast<bf16x8*>(xb + i) = load8(x + i);
}

// ---------------------------------------------------------------------------
// Weights fp32 [K][N] -> bf16 transposed [N][K] (K=1024), 64x64 LDS tiles.
// Segments: Wq 256 tiles | Wk 64 | Wv 64 | Wo 256  -> 640 blocks.
// ---------------------------------------------------------------------------
__global__ __launch_bounds__(256) void cvtT_k(
    const float* __restrict__ Wq, const float* __restrict__ Wk,
    const float* __restrict__ Wv, const float* __restrict__ Wo,
    bf16_t* __restrict__ wqT, bf16_t* __restrict__ wkT,
    bf16_t* __restrict__ wvT, bf16_t* __restrict__ woT) {
  __shared__ bf16_t Ts[64][72];
  const int b = blockIdx.x;
  const float* S;
  bf16_t* D;
  int N, idx;
  if (b < 256) { S = Wq; D = wqT; N = 1024; idx = b; }
  else if (b < 320) { S = Wk; D = wkT; N = 256; idx = b - 256; }
  else if (b < 384) { S = Wv; D = wvT; N = 256; idx = b - 320; }
  else { S = Wo; D = woT; N = 1024; idx = b - 384; }
  const int ntl = (N == 1024) ? 4 : 2;  // log2(n-tiles)
  const int kt0 = (idx >> ntl) * 64;
  const int n0 = (idx & ((1 << ntl) - 1)) * 64;
  const int tid = threadIdx.x;
#pragma unroll
  for (int i = 0; i < 2; ++i) {
    const int c = tid + 256 * i;
    const int row = c >> 3, col0 = (c & 7) * 8;
    *reinterpret_cast<bf16x8*>(&Ts[row][col0]) =
        load8(&S[(size_t)(kt0 + row) * N + n0 + col0]);
  }
  __syncthreads();
#pragma unroll
  for (int i = 0; i < 2; ++i) {
    const int c = tid + 256 * i;
    const int nrow = c >> 3, k0 = (c & 7) * 8;
    bf16x8 v;
#pragma unroll
    for (int j = 0; j < 8; ++j) v[j] = Ts[k0 + j][nrow];
    *reinterpret_cast<bf16x8*>(&D[(size_t)(n0 + nrow) * 1024 + kt0 + k0]) = v;
  }
}

// ---------------------------------------------------------------------------
// 128x128 GEMM body, B^T form: C = A[M,K] * BT[N,K]^T, all bf16, BK=32,
// software-pipelined staging, both operands staged as contiguous b128 rows.
// MFMA layouts (verified m89):
//   A: lane holds A[m=lane&15][k=(lane>>4)*8+j]
//   B: lane holds B[k=(lane>>4)*8+j][n=lane&15]  (= BT[n][k] rows)
//   C/D: row=(lane>>4)*4+reg, col=lane&15
// ---------------------------------------------------------------------------
template <typename OutT>
__device__ inline void gemm_bt_body(const bf16_t* __restrict__ A,
                                    const bf16_t* __restrict__ BT,
                                    OutT* __restrict__ C, int m0, int bt0,
                                    int K, int CN, int cn0, float alpha) {
  __shared__ __align__(16) bf16_t As[128][40];
  __shared__ __align__(16) bf16_t Bs[128][40];  // [n][k]

  const int tid = threadIdx.x;
  const int wave = tid >> 6, lane = tid & 63;
  const int quad = lane >> 4, l16 = lane & 15;
  const int moff = (wave & 1) * 64, noff = (wave >> 1) * 64;

  f32x4 acc[4][4];
#pragma unroll
  for (int mt = 0; mt < 4; ++mt)
#pragma unroll
    for (int nt = 0; nt < 4; ++nt) acc[mt][nt] = {0.f, 0.f, 0.f, 0.f};

  const int arow = tid >> 1, ak0 = (tid & 1) * 16;

  bf16x8 a0, a1, b0, b1;
  {
    const bf16_t* ap = &A[(size_t)(m0 + arow) * K + ak0];
    a0 = load8(ap); a1 = load8(ap + 8);
    const bf16_t* bp = &BT[(size_t)(bt0 + arow) * K + ak0];
    b0 = load8(bp); b1 = load8(bp + 8);
  }

  for (int k0 = 0; k0 < K; k0 += 32) {
    *reinterpret_cast<bf16x8*>(&As[arow][ak0]) = a0;
    *reinterpret_cast<bf16x8*>(&As[arow][ak0 + 8]) = a1;
    *reinterpret_cast<bf16x8*>(&Bs[arow][ak0]) = b0;
    *reinterpret_cast<bf16x8*>(&Bs[arow][ak0 + 8]) = b1;
    __syncthreads();
    if (k0 + 32 < K) {
      const bf16_t* ap = &A[(size_t)(m0 + arow) * K + k0 + 32 + ak0];
      a0 = load8(ap); a1 = load8(ap + 8);
      const bf16_t* bp = &BT[(size_t)(bt0 + arow) * K + k0 + 32 + ak0];
      b0 = load8(bp); b1 = load8(bp + 8);
    }
    bf16x8 af[4], bfr[4];
#pragma unroll
    for (int mt = 0; mt < 4; ++mt)
      af[mt] =
          *reinterpret_cast<const bf16x8*>(&As[moff + mt * 16 + l16][quad * 8]);
#pragma unroll
    for (int nt = 0; nt < 4; ++nt)
      bfr[nt] =
          *reinterpret_cast<const bf16x8*>(&Bs[noff + nt * 16 + l16][quad * 8]);
#pragma unroll
    for (int mt = 0; mt < 4; ++mt)
#pragma unroll
      for (int nt = 0; nt < 4; ++nt)
        acc[mt][nt] = __builtin_amdgcn_mfma_f32_16x16x32_bf16(
            af[mt], bfr[nt], acc[mt][nt], 0, 0, 0);
    __syncthreads();
  }

#pragma unroll
  for (int mt = 0; mt < 4; ++mt) {
    const int crow = m0 + moff + mt * 16 + quad * 4;
#pragma unroll
    for (int nt = 0; nt < 4; ++nt) {
      const int ccol = cn0 + noff + nt * 16 + l16;
#pragma unroll
      for (int r = 0; r < 4; ++r)
        C[(size_t)(crow + r) * CN + ccol] = (OutT)(acc[mt][nt][r] * alpha);
    }
  }
}

// Fused QKV projection: n-tiles [Wq 0..7 | Wk 8..9 | Wv 10..11], B^T weights.
// Q scale = 1/sqrt(64) * log2(e) so flash can use exp2 directly.
__global__ __launch_bounds__(256, 3) void qkv_k(
    const bf16_t* __restrict__ x, const bf16_t* __restrict__ wqT,
    const bf16_t* __restrict__ wkT, const bf16_t* __restrict__ wvT,
    bf16_t* __restrict__ Qo, bf16_t* __restrict__ Ko, bf16_t* __restrict__ Vo) {
  const int n0 = blockIdx.x * 128;
  const int m0 = blockIdx.y * 128;
  const bf16_t* BT;
  bf16_t* C;
  int CN, bn0;
  float alpha;
  if (n0 < 1024) {
    BT = wqT; C = Qo; CN = 1024; bn0 = n0;
    alpha = 0.18033688f;  // 0.125 * log2(e)
  } else if (n0 < 1280) {
    BT = wkT; C = Ko; CN = 256; bn0 = n0 - 1024; alpha = 1.0f;
  } else {
    BT = wvT; C = Vo; CN = 256; bn0 = n0 - 1280; alpha = 1.0f;
  }
  gemm_bt_body<bf16_t>(x, BT, C, m0, bn0, 1024, CN, bn0, alpha);
}

// Plain B^T GEMM (attn @ Wo^T^T).
template <typename OutT>
__global__ __launch_bounds__(256, 3) void gemm_bt_k(
    const bf16_t* __restrict__ A, const bf16_t* __restrict__ BT,
    OutT* __restrict__ C, int K, int N, float alpha) {
  gemm_bt_body<OutT>(A, BT, C, blockIdx.y * 128, blockIdx.x * 128, K, N,
                     blockIdx.x * 128, alpha);
}

// ---------------------------------------------------------------------------
// Transpose V [4096,256] -> VT[(g*4+kh)*64 + d][key].
// ---------------------------------------------------------------------------
__global__ __launch_bounds__(256) void transpose_v_k(
    const bf16_t* __restrict__ V, bf16_t* __restrict__ VT) {
  __shared__ bf16_t Vs[64][72];
  const int tid = threadIdx.x;
  const int kt0 = blockIdx.x * 64;
  const int ghk = blockIdx.y;  // g*4+kh
  const int g = ghk >> 2, kh = ghk & 3;
#pragma unroll
  for (int i = 0; i < 2; ++i) {
    const int c = tid + 256 * i;
    const int row = c >> 3, d0 = (c & 7) * 8;
    *reinterpret_cast<bf16x8*>(&Vs[row][d0]) = *reinterpret_cast<const bf16x8*>(
        &V[((size_t)(kt0 + row) * 2 + g) * 256 + kh * 64 + d0]);
  }
  __syncthreads();
#pragma unroll
  for (int i = 0; i < 2; ++i) {
    const int c = tid + 256 * i;
    const int d = c >> 3, k0 = (c & 7) * 8;
    bf16x8 v;
#pragma unroll
    for (int j = 0; j < 8; ++j) v[j] = Vs[k0 + j][d];
    *reinterpret_cast<bf16x8*>(&VT[((size_t)ghk * 64 + d) * 2048 + kt0 + k0]) =
        v;
  }
}

// ---------------------------------------------------------------------------
// Flash attention v9 = flash6 (2 waves x 32 q-rows, VGPR=100, no spills)
// with a per-CU balanced causal-T map. Diagnosis (r2): with linear-id%8 XCD
// round-robin, CU c gets per-XCD sequence n = i8+4*gh, n === c (mod 32) ->
// all 4 of its blocks share i8, i.e. the SAME T (4..128 iters per CU).
// Fix: rotate the i8-class by u=(gh>>3)&3 (the gh bits that vary across a
// CU's block set): i8e=(i8+u)&3. Each CU now hosts all four i8-classes ->
// exactly 66 key-tile iterations per CU; per-gh tile bijection preserved.
// Softmax uses exp2 (log2(e) folded into Q projection scale).
// ---------------------------------------------------------------------------
__global__ __launch_bounds__(128, 2) void flash9_k(
    const bf16_t* __restrict__ Q, const bf16_t* __restrict__ K,
    const bf16_t* __restrict__ VT, bf16_t* __restrict__ ATTN) {
  __shared__ __align__(16) bf16_t Ks[64][64];
  __shared__ __align__(16) bf16_t Vs[64][64];  // [d][key_local], swizzled
  __shared__ __align__(16) bf16_t Ps[2][32][64];

  const int tid = threadIdx.x;
  const int w = tid >> 6, lane = tid & 63;
  const int quad = lane >> 4, l16 = lane & 15;
  const int b = blockIdx.x;
  const int gh = blockIdx.y;
  const int j8 = b & 7;
  const int i8e = ((b >> 3) + (gh >> 3)) & 3;  // gh-rotated length class
  const int T = (i8e == 0) ? j8
              : (i8e == 1) ? (15 - j8)
              : (i8e == 2) ? (16 + j8)
                           : (31 - j8);
  const int g = gh >> 4, h = gh & 15, kh = h >> 2;
  const int qbase = T * 64 + w * 32;
  const int swz = ((l16 >> 2) & 3) << 4;
  const int rsw = l16 & 7;  // row-dependent K/V col-block swizzle key

  bf16x8 qf[2][2];
#pragma unroll
  for (int rg = 0; rg < 2; ++rg)
#pragma unroll
    for (int t = 0; t < 2; ++t)
      qf[rg][t] = *reinterpret_cast<const bf16x8*>(
          &Q[((size_t)(qbase + rg * 16 + l16) * 2 + g) * 1024 + h * 64 +
             t * 32 + quad * 8]);

  f32x4 O[2][4];
  f32x4 lp[2];
#pragma unroll
  for (int rg = 0; rg < 2; ++rg) {
    lp[rg] = {0.f, 0.f, 0.f, 0.f};
#pragma unroll
    for (int d = 0; d < 4; ++d) O[rg][d] = {0.f, 0.f, 0.f, 0.f};
  }

  bf16x8 kr[4], vr[4];
#pragma unroll
  for (int i = 0; i < 4; ++i) {
    const int c = tid + 128 * i;
    const int row = c >> 3, e0 = (c & 7) * 8;
    kr[i] = *reinterpret_cast<const bf16x8*>(
        &K[((size_t)(row)*2 + g) * 256 + kh * 64 + e0]);
    vr[i] = *reinterpret_cast<const bf16x8*>(
        &VT[((size_t)(g * 4 + kh) * 64 + row) * 2048 + e0]);
  }

  for (int kt = 0; kt <= T; ++kt) {
#pragma unroll
    for (int i = 0; i < 4; ++i) {
      const int c = tid + 128 * i;
      const int row = c >> 3;
      const int pb = (((c & 7) ^ (row & 7)) << 3);  // swizzled col block
      *reinterpret_cast<bf16x8*>(&Ks[row][pb]) = kr[i];
      *reinterpret_cast<bf16x8*>(&Vs[row][pb]) = vr[i];
    }
    __syncthreads();
    if (kt < T) {
      const int nt0 = (kt + 1) * 64;
#pragma unroll
      for (int i = 0; i < 4; ++i) {
        const int c = tid + 128 * i;
        const int row = c >> 3, e0 = (c & 7) * 8;
        kr[i] = *reinterpret_cast<const bf16x8*>(
            &K[((size_t)(nt0 + row) * 2 + g) * 256 + kh * 64 + e0]);
        vr[i] = *reinterpret_cast<const bf16x8*>(
            &VT[((size_t)(g * 4 + kh) * 64 + row) * 2048 + nt0 + e0]);
      }
    }

    f32x4 s[2][4];
    __builtin_amdgcn_s_setprio(1);
#pragma unroll
    for (int nt = 0; nt < 4; ++nt) {
      bf16x8 kf0 = *reinterpret_cast<const bf16x8*>(
          &Ks[nt * 16 + l16][(quad ^ rsw) << 3]);
      bf16x8 kf1 = *reinterpret_cast<const bf16x8*>(
          &Ks[nt * 16 + l16][((4 + quad) ^ rsw) << 3]);
#pragma unroll
      for (int rg = 0; rg < 2; ++rg) {
        f32x4 z = {0.f, 0.f, 0.f, 0.f};
        z = __builtin_amdgcn_mfma_f32_16x16x32_bf16(qf[rg][0], kf0, z, 0, 0, 0);
        s[rg][nt] =
            __builtin_amdgcn_mfma_f32_16x16x32_bf16(qf[rg][1], kf1, z, 0, 0, 0);
      }
    }
    __builtin_amdgcn_s_setprio(0);
    const bool diag = (kt == T);
#pragma unroll
    for (int rg = 0; rg < 2; ++rg) {
#pragma unroll
      for (int nt = 0; nt < 4; ++nt) {
        const int key = nt * 16 + l16;
#pragma unroll
        for (int r = 0; r < 4; ++r) {
          float p = exp2f(s[rg][nt][r]);
          if (diag && key > w * 32 + rg * 16 + quad * 4 + r) p = 0.f;
          lp[rg][r] += p;
          Ps[w][rg * 16 + quad * 4 + r][((nt ^ quad) << 4) + l16] = (bf16_t)p;
        }
      }
    }
    bf16x8 pf[2][2];
#pragma unroll
    for (int rg = 0; rg < 2; ++rg)
#pragma unroll
      for (int t = 0; t < 2; ++t)
        pf[rg][t] = *reinterpret_cast<const bf16x8*>(
            &Ps[w][rg * 16 + l16][(t * 32 + quad * 8) ^ swz]);
    __builtin_amdgcn_s_setprio(1);
#pragma unroll
    for (int dnt = 0; dnt < 4; ++dnt) {
      bf16x8 vf0 = *reinterpret_cast<const bf16x8*>(
          &Vs[dnt * 16 + l16][(quad ^ rsw) << 3]);
      bf16x8 vf1 = *reinterpret_cast<const bf16x8*>(
          &Vs[dnt * 16 + l16][((4 + quad) ^ rsw) << 3]);
#pragma unroll
      for (int rg = 0; rg < 2; ++rg) {
        O[rg][dnt] = __builtin_amdgcn_mfma_f32_16x16x32_bf16(
            pf[rg][0], vf0, O[rg][dnt], 0, 0, 0);
        O[rg][dnt] = __builtin_amdgcn_mfma_f32_16x16x32_bf16(
            pf[rg][1], vf1, O[rg][dnt], 0, 0, 0);
      }
    }
    __builtin_amdgcn_s_setprio(0);
    __syncthreads();
  }

#pragma unroll
  for (int rg = 0; rg < 2; ++rg) {
#pragma unroll
    for (int off = 1; off < 16; off <<= 1)
#pragma unroll
      for (int r = 0; r < 4; ++r) lp[rg][r] += __shfl_xor(lp[rg][r], off, 64);
#pragma unroll
    for (int r = 0; r < 4; ++r) {
      const float inv = 1.f / lp[rg][r];
      const int row = qbase + rg * 16 + quad * 4 + r;
#pragma unroll
      for (int dnt = 0; dnt < 4; ++dnt)
        ATTN[((size_t)row * 2 + g) * 1024 + h * 64 + dnt * 16 + l16] =
            (bf16_t)(O[rg][dnt][r] * inv);
    }
  }
}

// ---------------------------------------------------------------------------
extern "C" void kernel_launch(void* const* d_in, const int* in_sizes, int n_in,
                              void* d_out, int out_size, void* d_ws,
                              size_t ws_size, hipStream_t stream) {
  (void)in_sizes;
  (void)n_in;
  (void)out_size;
  (void)ws_size;

  const float* x = (const float*)d_in[0];   // [4096,1024] fp32
  const float* Wq = (const float*)d_in[1];  // [1024,1024]
  const float* Wk = (const float*)d_in[2];  // [1024,256]
  const float* Wv = (const float*)d_in[3];  // [1024,256]
  const float* Wo = (const float*)d_in[4];  // [1024,1024]
  float* out = (float*)d_out;               // [4096,1024] fp32 (16 MB)

  const size_t MB = 1024 * 1024;
  // d_out: [0,8M) Qtmp | [8M,10M) VT | [10M,13M) wqT/wkT/wvT | [13M,15M) Vo
  // (all dead before the final GEMM writes out; final GEMM reads only ws).
  char* ob = (char*)d_out;
  bf16_t* Qtmp = (bf16_t*)ob;
  bf16_t* VTws = (bf16_t*)(ob + 8 * MB);
  bf16_t* wqT = (bf16_t*)(ob + 10 * MB);
  bf16_t* wkT = (bf16_t*)(ob + 12 * MB);
  bf16_t* wvT = (bf16_t*)(ob + 12 * MB + 512 * 1024);
  bf16_t* Vws = (bf16_t*)(ob + 13 * MB);
  // ws (12 MB): [0,2M) K | [2M,4M) woT | [4M,12M) ATTN (xb borrows upfront).
  char* wb = (char*)d_ws;
  bf16_t* Kws = (bf16_t*)wb;
  bf16_t* woT = (bf16_t*)(wb + 2 * MB);
  bf16_t* ATTNws = (bf16_t*)(wb + 4 * MB);
  bf16_t* xb = ATTNws;  // 8 MB, dead once flash starts writing ATTN

  cvtx_k<<<dim3(2048), dim3(256), 0, stream>>>(x, xb);
  cvtT_k<<<dim3(640), dim3(256), 0, stream>>>(Wq, Wk, Wv, Wo, wqT, wkT, wvT,
                                              woT);
  qkv_k<<<dim3(12, 32), dim3(256), 0, stream>>>(xb, wqT, wkT, wvT, Qtmp, Kws,
                                                Vws);
  transpose_v_k<<<dim3(32, 8), dim3(256), 0, stream>>>(Vws, VTws);
  flash9_k<<<dim3(32, 32), dim3(128), 0, stream>>>(Qtmp, Kws, VTws, ATTNws);
  gemm_bt_k<float><<<dim3(8, 32), dim3(256), 0, stream>>>(ATTNws, woT, out,
                                                          1024, 1024, 1.0f);
}

// Round 4
// 169.748 us; speedup vs baseline: 1.4227x; 1.1051x over previous
//
#include <hip/hip_runtime.h>
#include <cstdint>
#include <cstddef>

typedef __bf16 bf16_t;
typedef bf16_t bf16x8 __attribute__((ext_vector_type(8)));
typedef float f32x4 __attribute__((ext_vector_type(4)));

__device__ inline bf16x8 load8(const float* p) {
  f32x4 a = *reinterpret_cast<const f32x4*>(p);
  f32x4 b = *reinterpret_cast<const f32x4*>(p + 4);
  bf16x8 r;
  r[0] = (bf16_t)a[0]; r[1] = (bf16_t)a[1];
  r[2] = (bf16_t)a[2]; r[3] = (bf16_t)a[3];
  r[4] = (bf16_t)b[0]; r[5] = (bf16_t)b[1];
  r[6] = (bf16_t)b[2]; r[7] = (bf16_t)b[3];
  return r;
}
__device__ inline bf16x8 load8(const bf16_t* p) {
  return *reinterpret_cast<const bf16x8*>(p);
}

// ---------------------------------------------------------------------------
// x fp32 -> bf16 (flat copy).
// ---------------------------------------------------------------------------
__global__ __launch_bounds__(256) void cvtx_k(const float* __restrict__ x,
                                              bf16_t* __restrict__ xb) {
  const size_t i = (size_t)blockIdx.x * 2048 + (size_t)threadIdx.x * 8;
  *reinterpret_cast<bf16x8*>(xb + i) = load8(x + i);
}

// ---------------------------------------------------------------------------
// Weights fp32 [K][N] -> bf16 transposed [N][K] (K=1024), 64x64 LDS tiles.
// Segments: Wq 256 tiles | Wk 64 | Wv 64 | Wo 256  -> 640 blocks.
// ---------------------------------------------------------------------------
__global__ __launch_bounds__(256) void cvtT_k(
    const float* __restrict__ Wq, const float* __restrict__ Wk,
    const float* __restrict__ Wv, const float* __restrict__ Wo,
    bf16_t* __restrict__ wqT, bf16_t* __restrict__ wkT,
    bf16_t* __restrict__ wvT, bf16_t* __restrict__ woT) {
  __shared__ bf16_t Ts[64][72];
  const int b = blockIdx.x;
  const float* S;
  bf16_t* D;
  int N, idx;
  if (b < 256) { S = Wq; D = wqT; N = 1024; idx = b; }
  else if (b < 320) { S = Wk; D = wkT; N = 256; idx = b - 256; }
  else if (b < 384) { S = Wv; D = wvT; N = 256; idx = b - 320; }
  else { S = Wo; D = woT; N = 1024; idx = b - 384; }
  const int ntl = (N == 1024) ? 4 : 2;  // log2(n-tiles)
  const int kt0 = (idx >> ntl) * 64;
  const int n0 = (idx & ((1 << ntl) - 1)) * 64;
  const int tid = threadIdx.x;
#pragma unroll
  for (int i = 0; i < 2; ++i) {
    const int c = tid + 256 * i;
    const int row = c >> 3, col0 = (c & 7) * 8;
    *reinterpret_cast<bf16x8*>(&Ts[row][col0]) =
        load8(&S[(size_t)(kt0 + row) * N + n0 + col0]);
  }
  __syncthreads();
#pragma unroll
  for (int i = 0; i < 2; ++i) {
    const int c = tid + 256 * i;
    const int nrow = c >> 3, k0 = (c & 7) * 8;
    bf16x8 v;
#pragma unroll
    for (int j = 0; j < 8; ++j) v[j] = Ts[k0 + j][nrow];
    *reinterpret_cast<bf16x8*>(&D[(size_t)(n0 + nrow) * 1024 + kt0 + k0]) = v;
  }
}

// ---------------------------------------------------------------------------
// 128x128 GEMM body, B^T form: C = A[M,K] * BT[N,K]^T, all bf16, BK=32,
// software-pipelined staging, both operands staged as contiguous b128 rows.
// MFMA layouts (verified m89):
//   A: lane holds A[m=lane&15][k=(lane>>4)*8+j]
//   B: lane holds B[k=(lane>>4)*8+j][n=lane&15]  (= BT[n][k] rows)
//   C/D: row=(lane>>4)*4+reg, col=lane&15
// ---------------------------------------------------------------------------
template <typename OutT>
__device__ inline void gemm_bt_body(const bf16_t* __restrict__ A,
                                    const bf16_t* __restrict__ BT,
                                    OutT* __restrict__ C, int m0, int bt0,
                                    int K, int CN, int cn0, float alpha) {
  __shared__ __align__(16) bf16_t As[128][40];
  __shared__ __align__(16) bf16_t Bs[128][40];  // [n][k]

  const int tid = threadIdx.x;
  const int wave = tid >> 6, lane = tid & 63;
  const int quad = lane >> 4, l16 = lane & 15;
  const int moff = (wave & 1) * 64, noff = (wave >> 1) * 64;

  f32x4 acc[4][4];
#pragma unroll
  for (int mt = 0; mt < 4; ++mt)
#pragma unroll
    for (int nt = 0; nt < 4; ++nt) acc[mt][nt] = {0.f, 0.f, 0.f, 0.f};

  const int arow = tid >> 1, ak0 = (tid & 1) * 16;

  bf16x8 a0, a1, b0, b1;
  {
    const bf16_t* ap = &A[(size_t)(m0 + arow) * K + ak0];
    a0 = load8(ap); a1 = load8(ap + 8);
    const bf16_t* bp = &BT[(size_t)(bt0 + arow) * K + ak0];
    b0 = load8(bp); b1 = load8(bp + 8);
  }

  for (int k0 = 0; k0 < K; k0 += 32) {
    *reinterpret_cast<bf16x8*>(&As[arow][ak0]) = a0;
    *reinterpret_cast<bf16x8*>(&As[arow][ak0 + 8]) = a1;
    *reinterpret_cast<bf16x8*>(&Bs[arow][ak0]) = b0;
    *reinterpret_cast<bf16x8*>(&Bs[arow][ak0 + 8]) = b1;
    __syncthreads();
    if (k0 + 32 < K) {
      const bf16_t* ap = &A[(size_t)(m0 + arow) * K + k0 + 32 + ak0];
      a0 = load8(ap); a1 = load8(ap + 8);
      const bf16_t* bp = &BT[(size_t)(bt0 + arow) * K + k0 + 32 + ak0];
      b0 = load8(bp); b1 = load8(bp + 8);
    }
    bf16x8 af[4], bfr[4];
#pragma unroll
    for (int mt = 0; mt < 4; ++mt)
      af[mt] =
          *reinterpret_cast<const bf16x8*>(&As[moff + mt * 16 + l16][quad * 8]);
#pragma unroll
    for (int nt = 0; nt < 4; ++nt)
      bfr[nt] =
          *reinterpret_cast<const bf16x8*>(&Bs[noff + nt * 16 + l16][quad * 8]);
#pragma unroll
    for (int mt = 0; mt < 4; ++mt)
#pragma unroll
      for (int nt = 0; nt < 4; ++nt)
        acc[mt][nt] = __builtin_amdgcn_mfma_f32_16x16x32_bf16(
            af[mt], bfr[nt], acc[mt][nt], 0, 0, 0);
    __syncthreads();
  }

#pragma unroll
  for (int mt = 0; mt < 4; ++mt) {
    const int crow = m0 + moff + mt * 16 + quad * 4;
#pragma unroll
    for (int nt = 0; nt < 4; ++nt) {
      const int ccol = cn0 + noff + nt * 16 + l16;
#pragma unroll
      for (int r = 0; r < 4; ++r)
        C[(size_t)(crow + r) * CN + ccol] = (OutT)(acc[mt][nt][r] * alpha);
    }
  }
}

// Fused QKV projection: n-tiles [Wq 0..7 | Wk 8..9 | Wv 10..11], B^T weights.
__global__ __launch_bounds__(256, 3) void qkv_k(
    const bf16_t* __restrict__ x, const bf16_t* __restrict__ wqT,
    const bf16_t* __restrict__ wkT, const bf16_t* __restrict__ wvT,
    bf16_t* __restrict__ Qo, bf16_t* __restrict__ Ko, bf16_t* __restrict__ Vo) {
  const int n0 = blockIdx.x * 128;
  const int m0 = blockIdx.y * 128;
  const bf16_t* BT;
  bf16_t* C;
  int CN, bn0;
  float alpha;
  if (n0 < 1024) {
    BT = wqT; C = Qo; CN = 1024; bn0 = n0; alpha = 0.125f;  // attn scale
  } else if (n0 < 1280) {
    BT = wkT; C = Ko; CN = 256; bn0 = n0 - 1024; alpha = 1.0f;
  } else {
    BT = wvT; C = Vo; CN = 256; bn0 = n0 - 1280; alpha = 1.0f;
  }
  gemm_bt_body<bf16_t>(x, BT, C, m0, bn0, 1024, CN, bn0, alpha);
}

// Plain B^T GEMM (attn @ Wo^T^T).
template <typename OutT>
__global__ __launch_bounds__(256, 3) void gemm_bt_k(
    const bf16_t* __restrict__ A, const bf16_t* __restrict__ BT,
    OutT* __restrict__ C, int K, int N, float alpha) {
  gemm_bt_body<OutT>(A, BT, C, blockIdx.y * 128, blockIdx.x * 128, K, N,
                     blockIdx.x * 128, alpha);
}

// ---------------------------------------------------------------------------
// Transpose V [4096,256] -> VT[(g*4+kh)*64 + d][key].
// ---------------------------------------------------------------------------
__global__ __launch_bounds__(256) void transpose_v_k(
    const bf16_t* __restrict__ V, bf16_t* __restrict__ VT) {
  __shared__ bf16_t Vs[64][72];
  const int tid = threadIdx.x;
  const int kt0 = blockIdx.x * 64;
  const int ghk = blockIdx.y;  // g*4+kh
  const int g = ghk >> 2, kh = ghk & 3;
#pragma unroll
  for (int i = 0; i < 2; ++i) {
    const int c = tid + 256 * i;
    const int row = c >> 3, d0 = (c & 7) * 8;
    *reinterpret_cast<bf16x8*>(&Vs[row][d0]) = *reinterpret_cast<const bf16x8*>(
        &V[((size_t)(kt0 + row) * 2 + g) * 256 + kh * 64 + d0]);
  }
  __syncthreads();
#pragma unroll
  for (int i = 0; i < 2; ++i) {
    const int c = tid + 256 * i;
    const int d = c >> 3, k0 = (c & 7) * 8;
    bf16x8 v;
#pragma unroll
    for (int j = 0; j < 8; ++j) v[j] = Vs[k0 + j][d];
    *reinterpret_cast<bf16x8*>(&VT[((size_t)ghk * 64 + d) * 2048 + kt0 + k0]) =
        v;
  }
}

// ---------------------------------------------------------------------------
// Flash attention v10 = flash8 structure (4 waves x 16 q-rows, flash6's
// 32-tile/528-iter geometry, 4096 waves -> 4 waves/SIMD) with the spill bug
// fixed: __launch_bounds__(256,4) caps VGPR at 128 (r2's (256,6) forced 40
// VGPR -> 61 MB scratch, WRITE_SIZE 69 MB). Live state ~80 VGPR fits clean.
// Keeps flash9's (neutral, verified) gh-rotated causal-T map and the
// flash6-verified __expf softmax.
// LDS 24 KB (Ks 8K + Vs 8K + Ps[4] 8K) -> 4 blocks/CU, 16 waves/CU.
// ---------------------------------------------------------------------------
__global__ __launch_bounds__(256, 4) void flash10_k(
    const bf16_t* __restrict__ Q, const bf16_t* __restrict__ K,
    const bf16_t* __restrict__ VT, bf16_t* __restrict__ ATTN) {
  __shared__ __align__(16) bf16_t Ks[64][64];
  __shared__ __align__(16) bf16_t Vs[64][64];  // [d][key_local], swizzled
  __shared__ __align__(16) bf16_t Ps[4][16][64];

  const int tid = threadIdx.x;
  const int w = tid >> 6, lane = tid & 63;
  const int quad = lane >> 4, l16 = lane & 15;
  const int b = blockIdx.x;  // 0..31
  const int gh = blockIdx.y;
  const int j8 = b & 7;
  const int i8e = ((b >> 3) + (gh >> 3)) & 3;  // gh-rotated length class
  const int T = (i8e == 0) ? j8
              : (i8e == 1) ? (15 - j8)
              : (i8e == 2) ? (16 + j8)
                           : (31 - j8);
  const int g = gh >> 4, h = gh & 15, kh = h >> 2;
  const int qrow0 = T * 64 + w * 16;  // wave's first query row
  const int swz = ((l16 >> 2) & 3) << 4;
  const int rsw = l16 & 7;  // row-dependent K/V col-block swizzle key

  bf16x8 qf[2];
#pragma unroll
  for (int t = 0; t < 2; ++t)
    qf[t] = *reinterpret_cast<const bf16x8*>(
        &Q[((size_t)(qrow0 + l16) * 2 + g) * 1024 + h * 64 + t * 32 +
           quad * 8]);

  f32x4 O[4];
  f32x4 lp = {0.f, 0.f, 0.f, 0.f};
#pragma unroll
  for (int d = 0; d < 4; ++d) O[d] = {0.f, 0.f, 0.f, 0.f};

  bf16x8 kr[2], vr[2];
#pragma unroll
  for (int i = 0; i < 2; ++i) {
    const int c = tid + 256 * i;
    const int row = c >> 3, e0 = (c & 7) * 8;
    kr[i] = *reinterpret_cast<const bf16x8*>(
        &K[((size_t)(row)*2 + g) * 256 + kh * 64 + e0]);
    vr[i] = *reinterpret_cast<const bf16x8*>(
        &VT[((size_t)(g * 4 + kh) * 64 + row) * 2048 + e0]);
  }

  for (int kt = 0; kt <= T; ++kt) {
#pragma unroll
    for (int i = 0; i < 2; ++i) {
      const int c = tid + 256 * i;
      const int row = c >> 3;
      const int pb = (((c & 7) ^ (row & 7)) << 3);  // swizzled col block
      *reinterpret_cast<bf16x8*>(&Ks[row][pb]) = kr[i];
      *reinterpret_cast<bf16x8*>(&Vs[row][pb]) = vr[i];
    }
    __syncthreads();
    if (kt < T) {
      const int nt0 = (kt + 1) * 64;
#pragma unroll
      for (int i = 0; i < 2; ++i) {
        const int c = tid + 256 * i;
        const int row = c >> 3, e0 = (c & 7) * 8;
        kr[i] = *reinterpret_cast<const bf16x8*>(
            &K[((size_t)(nt0 + row) * 2 + g) * 256 + kh * 64 + e0]);
        vr[i] = *reinterpret_cast<const bf16x8*>(
            &VT[((size_t)(g * 4 + kh) * 64 + row) * 2048 + nt0 + e0]);
      }
    }

    f32x4 s[4];
    __builtin_amdgcn_s_setprio(1);
#pragma unroll
    for (int nt = 0; nt < 4; ++nt) {
      bf16x8 kf0 = *reinterpret_cast<const bf16x8*>(
          &Ks[nt * 16 + l16][(quad ^ rsw) << 3]);
      bf16x8 kf1 = *reinterpret_cast<const bf16x8*>(
          &Ks[nt * 16 + l16][((4 + quad) ^ rsw) << 3]);
      f32x4 z = {0.f, 0.f, 0.f, 0.f};
      z = __builtin_amdgcn_mfma_f32_16x16x32_bf16(qf[0], kf0, z, 0, 0, 0);
      s[nt] = __builtin_amdgcn_mfma_f32_16x16x32_bf16(qf[1], kf1, z, 0, 0, 0);
    }
    __builtin_amdgcn_s_setprio(0);
    const bool diag = (kt == T);
    const int qloc = w * 16 + quad * 4;  // wave-local q row vs tile keys
#pragma unroll
    for (int nt = 0; nt < 4; ++nt) {
      const int key = nt * 16 + l16;
#pragma unroll
      for (int r = 0; r < 4; ++r) {
        float p = __expf(s[nt][r]);
        if (diag && key > qloc + r) p = 0.f;
        lp[r] += p;
        Ps[w][quad * 4 + r][((nt ^ quad) << 4) + l16] = (bf16_t)p;
      }
    }
    bf16x8 pf[2];
#pragma unroll
    for (int t = 0; t < 2; ++t)
      pf[t] = *reinterpret_cast<const bf16x8*>(
          &Ps[w][l16][(t * 32 + quad * 8) ^ swz]);
    __builtin_amdgcn_s_setprio(1);
#pragma unroll
    for (int dnt = 0; dnt < 4; ++dnt) {
      bf16x8 vf0 = *reinterpret_cast<const bf16x8*>(
          &Vs[dnt * 16 + l16][(quad ^ rsw) << 3]);
      bf16x8 vf1 = *reinterpret_cast<const bf16x8*>(
          &Vs[dnt * 16 + l16][((4 + quad) ^ rsw) << 3]);
      O[dnt] = __builtin_amdgcn_mfma_f32_16x16x32_bf16(pf[0], vf0, O[dnt], 0,
                                                       0, 0);
      O[dnt] = __builtin_amdgcn_mfma_f32_16x16x32_bf16(pf[1], vf1, O[dnt], 0,
                                                       0, 0);
    }
    __builtin_amdgcn_s_setprio(0);
    __syncthreads();
  }

#pragma unroll
  for (int off = 1; off < 16; off <<= 1)
#pragma unroll
    for (int r = 0; r < 4; ++r) lp[r] += __shfl_xor(lp[r], off, 64);
#pragma unroll
  for (int r = 0; r < 4; ++r) {
    const float inv = 1.f / lp[r];
    const int row = qrow0 + quad * 4 + r;
#pragma unroll
    for (int dnt = 0; dnt < 4; ++dnt)
      ATTN[((size_t)row * 2 + g) * 1024 + h * 64 + dnt * 16 + l16] =
          (bf16_t)(O[dnt][r] * inv);
  }
}

// ---------------------------------------------------------------------------
extern "C" void kernel_launch(void* const* d_in, const int* in_sizes, int n_in,
                              void* d_out, int out_size, void* d_ws,
                              size_t ws_size, hipStream_t stream) {
  (void)in_sizes;
  (void)n_in;
  (void)out_size;
  (void)ws_size;

  const float* x = (const float*)d_in[0];   // [4096,1024] fp32
  const float* Wq = (const float*)d_in[1];  // [1024,1024]
  const float* Wk = (const float*)d_in[2];  // [1024,256]
  const float* Wv = (const float*)d_in[3];  // [1024,256]
  const float* Wo = (const float*)d_in[4];  // [1024,1024]
  float* out = (float*)d_out;               // [4096,1024] fp32 (16 MB)

  const size_t MB = 1024 * 1024;
  // d_out: [0,8M) Qtmp | [8M,10M) VT | [10M,13M) wqT/wkT/wvT | [13M,15M) Vo
  // (all dead before the final GEMM writes out; final GEMM reads only ws).
  char* ob = (char*)d_out;
  bf16_t* Qtmp = (bf16_t*)ob;
  bf16_t* VTws = (bf16_t*)(ob + 8 * MB);
  bf16_t* wqT = (bf16_t*)(ob + 10 * MB);
  bf16_t* wkT = (bf16_t*)(ob + 12 * MB);
  bf16_t* wvT = (bf16_t*)(ob + 12 * MB + 512 * 1024);
  bf16_t* Vws = (bf16_t*)(ob + 13 * MB);
  // ws (12 MB): [0,2M) K | [2M,4M) woT | [4M,12M) ATTN (xb borrows upfront).
  char* wb = (char*)d_ws;
  bf16_t* Kws = (bf16_t*)wb;
  bf16_t* woT = (bf16_t*)(wb + 2 * MB);
  bf16_t* ATTNws = (bf16_t*)(wb + 4 * MB);
  bf16_t* xb = ATTNws;  // 8 MB, dead once flash starts writing ATTN

  cvtx_k<<<dim3(2048), dim3(256), 0, stream>>>(x, xb);
  cvtT_k<<<dim3(640), dim3(256), 0, stream>>>(Wq, Wk, Wv, Wo, wqT, wkT, wvT,
                                              woT);
  qkv_k<<<dim3(12, 32), dim3(256), 0, stream>>>(xb, wqT, wkT, wvT, Qtmp, Kws,
                                                Vws);
  transpose_v_k<<<dim3(32, 8), dim3(256), 0, stream>>>(Vws, VTws);
  flash10_k<<<dim3(32, 32), dim3(256), 0, stream>>>(Qtmp, Kws, VTws, ATTNws);
  gemm_bt_k<float><<<dim3(8, 32), dim3(256), 0, stream>>>(ATTNws, woT, out,
                                                          1024, 1024, 1.0f);
}

// Round 5
// 166.255 us; speedup vs baseline: 1.4526x; 1.0210x over previous
//
#include <hip/hip_runtime.h>
#include <cstdint>
#include <cstddef>

typedef __bf16 bf16_t;
typedef bf16_t bf16x8 __attribute__((ext_vector_type(8)));
typedef float f32x4 __attribute__((ext_vector_type(4)));

__device__ inline bf16x8 load8(const float* p) {
  f32x4 a = *reinterpret_cast<const f32x4*>(p);
  f32x4 b = *reinterpret_cast<const f32x4*>(p + 4);
  bf16x8 r;
  r[0] = (bf16_t)a[0]; r[1] = (bf16_t)a[1];
  r[2] = (bf16_t)a[2]; r[3] = (bf16_t)a[3];
  r[4] = (bf16_t)b[0]; r[5] = (bf16_t)b[1];
  r[6] = (bf16_t)b[2]; r[7] = (bf16_t)b[3];
  return r;
}
__device__ inline bf16x8 load8(const bf16_t* p) {
  return *reinterpret_cast<const bf16x8*>(p);
}

// Async global->LDS 16B copy (gfx950). LDS dst is wave-uniform base +
// lane*16; global src is per-lane.
__device__ inline void gload_lds16(const bf16_t* g, bf16_t* l) {
  __builtin_amdgcn_global_load_lds(
      (const __attribute__((address_space(1))) void*)g,
      (__attribute__((address_space(3))) void*)l, 16, 0, 0);
}

// ---------------------------------------------------------------------------
// x fp32 -> bf16 (flat copy).
// ---------------------------------------------------------------------------
__global__ __launch_bounds__(256) void cvtx_k(const float* __restrict__ x,
                                              bf16_t* __restrict__ xb) {
  const size_t i = (size_t)blockIdx.x * 2048 + (size_t)threadIdx.x * 8;
  *reinterpret_cast<bf16x8*>(xb + i) = load8(x + i);
}

// ---------------------------------------------------------------------------
// Weights fp32 [K][N] -> bf16 transposed [N][K] (K=1024), 64x64 LDS tiles.
// Segments: Wq 256 tiles | Wk 64 | Wv 64 | Wo 256  -> 640 blocks.
// ---------------------------------------------------------------------------
__global__ __launch_bounds__(256) void cvtT_k(
    const float* __restrict__ Wq, const float* __restrict__ Wk,
    const float* __restrict__ Wv, const float* __restrict__ Wo,
    bf16_t* __restrict__ wqT, bf16_t* __restrict__ wkT,
    bf16_t* __restrict__ wvT, bf16_t* __restrict__ woT) {
  __shared__ bf16_t Ts[64][72];
  const int b = blockIdx.x;
  const float* S;
  bf16_t* D;
  int N, idx;
  if (b < 256) { S = Wq; D = wqT; N = 1024; idx = b; }
  else if (b < 320) { S = Wk; D = wkT; N = 256; idx = b - 256; }
  else if (b < 384) { S = Wv; D = wvT; N = 256; idx = b - 320; }
  else { S = Wo; D = woT; N = 1024; idx = b - 384; }
  const int ntl = (N == 1024) ? 4 : 2;  // log2(n-tiles)
  const int kt0 = (idx >> ntl) * 64;
  const int n0 = (idx & ((1 << ntl) - 1)) * 64;
  const int tid = threadIdx.x;
#pragma unroll
  for (int i = 0; i < 2; ++i) {
    const int c = tid + 256 * i;
    const int row = c >> 3, col0 = (c & 7) * 8;
    *reinterpret_cast<bf16x8*>(&Ts[row][col0]) =
        load8(&S[(size_t)(kt0 + row) * N + n0 + col0]);
  }
  __syncthreads();
#pragma unroll
  for (int i = 0; i < 2; ++i) {
    const int c = tid + 256 * i;
    const int nrow = c >> 3, k0 = (c & 7) * 8;
    bf16x8 v;
#pragma unroll
    for (int j = 0; j < 8; ++j) v[j] = Ts[k0 + j][nrow];
    *reinterpret_cast<bf16x8*>(&D[(size_t)(n0 + nrow) * 1024 + kt0 + k0]) = v;
  }
}

// ---------------------------------------------------------------------------
// 128x128 GEMM body, B^T form: C = A[M,K] * BT[N,K]^T, all bf16, BK=32.
// v2: async global_load_lds staging (m97-style, guide ladder step 3), LDS
// double-buffered, ONE barrier per K-step; loads for tile k+1 fly during
// MFMA on tile k. Linear LDS [128][32] (global_load_lds needs contiguous
// dst) with k-block XOR swizzle cb ^= (row>>1)&3 applied inversely on the
// per-lane GLOBAL src (rule 21: both-sides-or-neither). ds_read_b128 start
// banks: (16r + 4(quad^((r>>1)&3)))%32 -> 8 distinct multiples of 4 per
// 16-lane group = conflict-free (same spread as old +8 pad).
// MFMA layouts (verified m89):
//   A: lane holds A[m=lane&15][k=(lane>>4)*8+j]
//   B: lane holds B[k=(lane>>4)*8+j][n=lane&15]  (= BT[n][k] rows)
//   C/D: row=(lane>>4)*4+reg, col=lane&15
// ---------------------------------------------------------------------------
__device__ inline void stage_glds(const bf16_t* __restrict__ G, int grow0,
                                  int gK, int k0, bf16_t* lds, int w, int l) {
  // 2 instructions per wave; each stages 16 rows x 32 cols (1 KiB).
#pragma unroll
  for (int i = 0; i < 2; ++i) {
    const int seg = w * 2 + i;              // 0..7
    const int r = (seg << 4) + (l >> 2);    // tile row 0..127
    const int cb = (l & 3) ^ ((r >> 1) & 3);  // swizzled global k-block
    gload_lds16(G + (size_t)(grow0 + r) * gK + k0 + cb * 8, lds + (seg << 9));
  }
}

template <typename OutT>
__device__ inline void gemm_bt_body(const bf16_t* __restrict__ A,
                                    const bf16_t* __restrict__ BT,
                                    OutT* __restrict__ C, int m0, int bt0,
                                    int K, int CN, int cn0, float alpha) {
  __shared__ __align__(16) bf16_t As[2][128][32];
  __shared__ __align__(16) bf16_t Bs[2][128][32];  // [n][k]

  const int tid = threadIdx.x;
  const int wave = tid >> 6, lane = tid & 63;
  const int quad = lane >> 4, l16 = lane & 15;
  const int moff = (wave & 1) * 64, noff = (wave >> 1) * 64;

  f32x4 acc[4][4];
#pragma unroll
  for (int mt = 0; mt < 4; ++mt)
#pragma unroll
    for (int nt = 0; nt < 4; ++nt) acc[mt][nt] = {0.f, 0.f, 0.f, 0.f};

  stage_glds(A, m0, K, 0, &As[0][0][0], wave, lane);
  stage_glds(BT, bt0, K, 0, &Bs[0][0][0], wave, lane);

  for (int k0 = 0; k0 < K; k0 += 32) {
    const int c = (k0 >> 5) & 1;
    __syncthreads();  // vmcnt(0) drain: buffer c ready; buffer c^1 free
    if (k0 + 32 < K) {
      stage_glds(A, m0, K, k0 + 32, &As[c ^ 1][0][0], wave, lane);
      stage_glds(BT, bt0, K, k0 + 32, &Bs[c ^ 1][0][0], wave, lane);
    }
    bf16x8 af[4], bfr[4];
#pragma unroll
    for (int mt = 0; mt < 4; ++mt) {
      const int row = moff + mt * 16 + l16;
      af[mt] = *reinterpret_cast<const bf16x8*>(
          &As[c][row][(quad ^ ((row >> 1) & 3)) * 8]);
    }
#pragma unroll
    for (int nt = 0; nt < 4; ++nt) {
      const int row = noff + nt * 16 + l16;
      bfr[nt] = *reinterpret_cast<const bf16x8*>(
          &Bs[c][row][(quad ^ ((row >> 1) & 3)) * 8]);
    }
#pragma unroll
    for (int mt = 0; mt < 4; ++mt)
#pragma unroll
      for (int nt = 0; nt < 4; ++nt)
        acc[mt][nt] = __builtin_amdgcn_mfma_f32_16x16x32_bf16(
            af[mt], bfr[nt], acc[mt][nt], 0, 0, 0);
  }

#pragma unroll
  for (int mt = 0; mt < 4; ++mt) {
    const int crow = m0 + moff + mt * 16 + quad * 4;
#pragma unroll
    for (int nt = 0; nt < 4; ++nt) {
      const int ccol = cn0 + noff + nt * 16 + l16;
#pragma unroll
      for (int r = 0; r < 4; ++r)
        C[(size_t)(crow + r) * CN + ccol] = (OutT)(acc[mt][nt][r] * alpha);
    }
  }
}

// Fused QKV projection: n-tiles [Wq 0..7 | Wk 8..9 | Wv 10..11], B^T weights.
__global__ __launch_bounds__(256, 3) void qkv_k(
    const bf16_t* __restrict__ x, const bf16_t* __restrict__ wqT,
    const bf16_t* __restrict__ wkT, const bf16_t* __restrict__ wvT,
    bf16_t* __restrict__ Qo, bf16_t* __restrict__ Ko, bf16_t* __restrict__ Vo) {
  const int n0 = blockIdx.x * 128;
  const int m0 = blockIdx.y * 128;
  const bf16_t* BT;
  bf16_t* C;
  int CN, bn0;
  float alpha;
  if (n0 < 1024) {
    BT = wqT; C = Qo; CN = 1024; bn0 = n0; alpha = 0.125f;  // attn scale
  } else if (n0 < 1280) {
    BT = wkT; C = Ko; CN = 256; bn0 = n0 - 1024; alpha = 1.0f;
  } else {
    BT = wvT; C = Vo; CN = 256; bn0 = n0 - 1280; alpha = 1.0f;
  }
  gemm_bt_body<bf16_t>(x, BT, C, m0, bn0, 1024, CN, bn0, alpha);
}

// Plain B^T GEMM (attn @ Wo^T^T).
template <typename OutT>
__global__ __launch_bounds__(256, 3) void gemm_bt_k(
    const bf16_t* __restrict__ A, const bf16_t* __restrict__ BT,
    OutT* __restrict__ C, int K, int N, float alpha) {
  gemm_bt_body<OutT>(A, BT, C, blockIdx.y * 128, blockIdx.x * 128, K, N,
                     blockIdx.x * 128, alpha);
}

// ---------------------------------------------------------------------------
// Transpose V [4096,256] -> VT[(g*4+kh)*64 + d][key].
// ---------------------------------------------------------------------------
__global__ __launch_bounds__(256) void transpose_v_k(
    const bf16_t* __restrict__ V, bf16_t* __restrict__ VT) {
  __shared__ bf16_t Vs[64][72];
  const int tid = threadIdx.x;
  const int kt0 = blockIdx.x * 64;
  const int ghk = blockIdx.y;  // g*4+kh
  const int g = ghk >> 2, kh = ghk & 3;
#pragma unroll
  for (int i = 0; i < 2; ++i) {
    const int c = tid + 256 * i;
    const int row = c >> 3, d0 = (c & 7) * 8;
    *reinterpret_cast<bf16x8*>(&Vs[row][d0]) = *reinterpret_cast<const bf16x8*>(
        &V[((size_t)(kt0 + row) * 2 + g) * 256 + kh * 64 + d0]);
  }
  __syncthreads();
#pragma unroll
  for (int i = 0; i < 2; ++i) {
    const int c = tid + 256 * i;
    const int d = c >> 3, k0 = (c & 7) * 8;
    bf16x8 v;
#pragma unroll
    for (int j = 0; j < 8; ++j) v[j] = Vs[k0 + j][d];
    *reinterpret_cast<bf16x8*>(&VT[((size_t)ghk * 64 + d) * 2048 + kt0 + k0]) =
        v;
  }
}

// ---------------------------------------------------------------------------
// Flash attention v10 (verified r4: 169.7 µs e2e, no spills): 4 waves x 16
// q-rows, flash6's 32-tile/528-iter geometry, 4096 waves -> 4 waves/SIMD.
// __launch_bounds__(256,4) caps VGPR at 128 (live state ~80, no scratch).
// gh-rotated causal-T map; __expf softmax.
// LDS 24 KB (Ks 8K + Vs 8K + Ps[4] 8K) -> 4 blocks/CU, 16 waves/CU.
// ---------------------------------------------------------------------------
__global__ __launch_bounds__(256, 4) void flash10_k(
    const bf16_t* __restrict__ Q, const bf16_t* __restrict__ K,
    const bf16_t* __restrict__ VT, bf16_t* __restrict__ ATTN) {
  __shared__ __align__(16) bf16_t Ks[64][64];
  __shared__ __align__(16) bf16_t Vs[64][64];  // [d][key_local], swizzled
  __shared__ __align__(16) bf16_t Ps[4][16][64];

  const int tid = threadIdx.x;
  const int w = tid >> 6, lane = tid & 63;
  const int quad = lane >> 4, l16 = lane & 15;
  const int b = blockIdx.x;  // 0..31
  const int gh = blockIdx.y;
  const int j8 = b & 7;
  const int i8e = ((b >> 3) + (gh >> 3)) & 3;  // gh-rotated length class
  const int T = (i8e == 0) ? j8
              : (i8e == 1) ? (15 - j8)
              : (i8e == 2) ? (16 + j8)
                           : (31 - j8);
  const int g = gh >> 4, h = gh & 15, kh = h >> 2;
  const int qrow0 = T * 64 + w * 16;  // wave's first query row
  const int swz = ((l16 >> 2) & 3) << 4;
  const int rsw = l16 & 7;  // row-dependent K/V col-block swizzle key

  bf16x8 qf[2];
#pragma unroll
  for (int t = 0; t < 2; ++t)
    qf[t] = *reinterpret_cast<const bf16x8*>(
        &Q[((size_t)(qrow0 + l16) * 2 + g) * 1024 + h * 64 + t * 32 +
           quad * 8]);

  f32x4 O[4];
  f32x4 lp = {0.f, 0.f, 0.f, 0.f};
#pragma unroll
  for (int d = 0; d < 4; ++d) O[d] = {0.f, 0.f, 0.f, 0.f};

  bf16x8 kr[2], vr[2];
#pragma unroll
  for (int i = 0; i < 2; ++i) {
    const int c = tid + 256 * i;
    const int row = c >> 3, e0 = (c & 7) * 8;
    kr[i] = *reinterpret_cast<const bf16x8*>(
        &K[((size_t)(row)*2 + g) * 256 + kh * 64 + e0]);
    vr[i] = *reinterpret_cast<const bf16x8*>(
        &VT[((size_t)(g * 4 + kh) * 64 + row) * 2048 + e0]);
  }

  for (int kt = 0; kt <= T; ++kt) {
#pragma unroll
    for (int i = 0; i < 2; ++i) {
      const int c = tid + 256 * i;
      const int row = c >> 3;
      const int pb = (((c & 7) ^ (row & 7)) << 3);  // swizzled col block
      *reinterpret_cast<bf16x8*>(&Ks[row][pb]) = kr[i];
      *reinterpret_cast<bf16x8*>(&Vs[row][pb]) = vr[i];
    }
    __syncthreads();
    if (kt < T) {
      const int nt0 = (kt + 1) * 64;
#pragma unroll
      for (int i = 0; i < 2; ++i) {
        const int c = tid + 256 * i;
        const int row = c >> 3, e0 = (c & 7) * 8;
        kr[i] = *reinterpret_cast<const bf16x8*>(
            &K[((size_t)(nt0 + row) * 2 + g) * 256 + kh * 64 + e0]);
        vr[i] = *reinterpret_cast<const bf16x8*>(
            &VT[((size_t)(g * 4 + kh) * 64 + row) * 2048 + nt0 + e0]);
      }
    }

    f32x4 s[4];
    __builtin_amdgcn_s_setprio(1);
#pragma unroll
    for (int nt = 0; nt < 4; ++nt) {
      bf16x8 kf0 = *reinterpret_cast<const bf16x8*>(
          &Ks[nt * 16 + l16][(quad ^ rsw) << 3]);
      bf16x8 kf1 = *reinterpret_cast<const bf16x8*>(
          &Ks[nt * 16 + l16][((4 + quad) ^ rsw) << 3]);
      f32x4 z = {0.f, 0.f, 0.f, 0.f};
      z = __builtin_amdgcn_mfma_f32_16x16x32_bf16(qf[0], kf0, z, 0, 0, 0);
      s[nt] = __builtin_amdgcn_mfma_f32_16x16x32_bf16(qf[1], kf1, z, 0, 0, 0);
    }
    __builtin_amdgcn_s_setprio(0);
    const bool diag = (kt == T);
    const int qloc = w * 16 + quad * 4;  // wave-local q row vs tile keys
#pragma unroll
    for (int nt = 0; nt < 4; ++nt) {
      const int key = nt * 16 + l16;
#pragma unroll
      for (int r = 0; r < 4; ++r) {
        float p = __expf(s[nt][r]);
        if (diag && key > qloc + r) p = 0.f;
        lp[r] += p;
        Ps[w][quad * 4 + r][((nt ^ quad) << 4) + l16] = (bf16_t)p;
      }
    }
    bf16x8 pf[2];
#pragma unroll
    for (int t = 0; t < 2; ++t)
      pf[t] = *reinterpret_cast<const bf16x8*>(
          &Ps[w][l16][(t * 32 + quad * 8) ^ swz]);
    __builtin_amdgcn_s_setprio(1);
#pragma unroll
    for (int dnt = 0; dnt < 4; ++dnt) {
      bf16x8 vf0 = *reinterpret_cast<const bf16x8*>(
          &Vs[dnt * 16 + l16][(quad ^ rsw) << 3]);
      bf16x8 vf1 = *reinterpret_cast<const bf16x8*>(
          &Vs[dnt * 16 + l16][((4 + quad) ^ rsw) << 3]);
      O[dnt] = __builtin_amdgcn_mfma_f32_16x16x32_bf16(pf[0], vf0, O[dnt], 0,
                                                       0, 0);
      O[dnt] = __builtin_amdgcn_mfma_f32_16x16x32_bf16(pf[1], vf1, O[dnt], 0,
                                                       0, 0);
    }
    __builtin_amdgcn_s_setprio(0);
    __syncthreads();
  }

#pragma unroll
  for (int off = 1; off < 16; off <<= 1)
#pragma unroll
    for (int r = 0; r < 4; ++r) lp[r] += __shfl_xor(lp[r], off, 64);
#pragma unroll
  for (int r = 0; r < 4; ++r) {
    const float inv = 1.f / lp[r];
    const int row = qrow0 + quad * 4 + r;
#pragma unroll
    for (int dnt = 0; dnt < 4; ++dnt)
      ATTN[((size_t)row * 2 + g) * 1024 + h * 64 + dnt * 16 + l16] =
          (bf16_t)(O[dnt][r] * inv);
  }
}

// ---------------------------------------------------------------------------
extern "C" void kernel_launch(void* const* d_in, const int* in_sizes, int n_in,
                              void* d_out, int out_size, void* d_ws,
                              size_t ws_size, hipStream_t stream) {
  (void)in_sizes;
  (void)n_in;
  (void)out_size;
  (void)ws_size;

  const float* x = (const float*)d_in[0];   // [4096,1024] fp32
  const float* Wq = (const float*)d_in[1];  // [1024,1024]
  const float* Wk = (const float*)d_in[2];  // [1024,256]
  const float* Wv = (const float*)d_in[3];  // [1024,256]
  const float* Wo = (const float*)d_in[4];  // [1024,1024]
  float* out = (float*)d_out;               // [4096,1024] fp32 (16 MB)

  const size_t MB = 1024 * 1024;
  // d_out: [0,8M) Qtmp | [8M,10M) VT | [10M,13M) wqT/wkT/wvT | [13M,15M) Vo
  // (all dead before the final GEMM writes out; final GEMM reads only ws).
  char* ob = (char*)d_out;
  bf16_t* Qtmp = (bf16_t*)ob;
  bf16_t* VTws = (bf16_t*)(ob + 8 * MB);
  bf16_t* wqT = (bf16_t*)(ob + 10 * MB);
  bf16_t* wkT = (bf16_t*)(ob + 12 * MB);
  bf16_t* wvT = (bf16_t*)(ob + 12 * MB + 512 * 1024);
  bf16_t* Vws = (bf16_t*)(ob + 13 * MB);
  // ws (12 MB): [0,2M) K | [2M,4M) woT | [4M,12M) ATTN (xb borrows upfront).
  char* wb = (char*)d_ws;
  bf16_t* Kws = (bf16_t*)wb;
  bf16_t* woT = (bf16_t*)(wb + 2 * MB);
  bf16_t* ATTNws = (bf16_t*)(wb + 4 * MB);
  bf16_t* xb = ATTNws;  // 8 MB, dead once flash starts writing ATTN

  cvtx_k<<<dim3(2048), dim3(256), 0, stream>>>(x, xb);
  cvtT_k<<<dim3(640), dim3(256), 0, stream>>>(Wq, Wk, Wv, Wo, wqT, wkT, wvT,
                                              woT);
  qkv_k<<<dim3(12, 32), dim3(256), 0, stream>>>(xb, wqT, wkT, wvT, Qtmp, Kws,
                                                Vws);
  transpose_v_k<<<dim3(32, 8), dim3(256), 0, stream>>>(Vws, VTws);
  flash10_k<<<dim3(32, 32), dim3(256), 0, stream>>>(Qtmp, Kws, VTws, ATTNws);
  gemm_bt_k<float><<<dim3(8, 32), dim3(256), 0, stream>>>(ATTNws, woT, out,
                                                          1024, 1024, 1.0f);
}